// Round 1
// 647.373 us; speedup vs baseline: 1.0328x; 1.0328x over previous
//
#include <hip/hip_runtime.h>
#include <hip/hip_bf16.h>
#include <stdint.h>

// AttentionGate on MI355X.
// Pipeline: K1 (MFMA bf16 convs + group stats, reg-prefetch pipelined,
//               interleaved (g,x) uint store) ->
//           K3 (wave-cooperative gate: leaky+psi dot + psi stats; GN consts inline) ->
//           K4 (sigmoid GN + x*psi).
// ws layout: wsp uint [2][NSP][64] (128MiB) | ppre f32 (2MiB) | stats 256B | psiSt 16B

#define DEV __device__ __forceinline__

typedef __attribute__((ext_vector_type(8))) short short8;
typedef __attribute__((ext_vector_type(4))) float floatx4;

constexpr int CG = 128;            // g in-channels
constexpr int CX = 64;             // x in-channels
constexpr int CO = 64;             // inter channels
constexpr int NSP = 64 * 64 * 64;  // 262144 spatial per batch
constexpr int GROUPS = 8;
constexpr float EPS = 1e-5f;

constexpr int LGS = 136;  // lG row stride (ushort): 128+8 pad
constexpr int LXS = 72;   // lX row stride: 64+8 pad
constexpr int TS  = 64;   // spatial tile
constexpr int TPB = 8;    // tiles per block -> block spans 512 spatial

DEV unsigned short f2bf(float f) {
  union { float f; uint32_t u; } v; v.f = f;
  uint32_t r = v.u + 0x7fffu + ((v.u >> 16) & 1u);
  return (unsigned short)(r >> 16);
}
DEV float bf2f(uint32_t h) {
  union { uint32_t u; float f; } v; v.u = h << 16;
  return v.f;
}

// ---------------- K1: convs via MFMA + group stats ----------------
// Register-prefetch pipeline: global loads for tile t+1 are issued right
// after the staging barrier of tile t, so they are in flight under the
// MFMA+store phase (~12 KB/wave outstanding -> HBM duty stays high).
__global__ __launch_bounds__(256, 4)
void k1_conv(const float* __restrict__ g, const float* __restrict__ x,
             const float* __restrict__ wg, const float* __restrict__ wx,
             uint32_t* __restrict__ outp, float* __restrict__ stats)
{
  __shared__ unsigned short lG[TS * LGS];
  __shared__ unsigned short lX[TS * LXS];

  const int tid  = threadIdx.x;
  const int wave = tid >> 6;
  const int lane = tid & 63;
  const int l16  = lane & 15;
  const int quad = lane >> 4;
  const int batch = blockIdx.x >> 9;              // 512 blocks per batch
  const int sblk  = (blockIdx.x & 511) * (TS * TPB);

  // A-fragments: lane holds A[m=lane&15][k=quad*8+j]
  const int ocb = wave * 16;
  short8 fg[4], fx[2];
  {
    const float* wr = wg + (size_t)(ocb + l16) * CG + quad * 8;
#pragma unroll
    for (int kk = 0; kk < 4; ++kk) {
      floatx4 u0 = *(const floatx4*)(wr + kk * 32);
      floatx4 u1 = *(const floatx4*)(wr + kk * 32 + 4);
      fg[kk][0] = (short)f2bf(u0[0]); fg[kk][1] = (short)f2bf(u0[1]);
      fg[kk][2] = (short)f2bf(u0[2]); fg[kk][3] = (short)f2bf(u0[3]);
      fg[kk][4] = (short)f2bf(u1[0]); fg[kk][5] = (short)f2bf(u1[1]);
      fg[kk][6] = (short)f2bf(u1[2]); fg[kk][7] = (short)f2bf(u1[3]);
    }
    const float* xr = wx + (size_t)(ocb + l16) * CX + quad * 8;
#pragma unroll
    for (int kk = 0; kk < 2; ++kk) {
      floatx4 u0 = *(const floatx4*)(xr + kk * 32);
      floatx4 u1 = *(const floatx4*)(xr + kk * 32 + 4);
      fx[kk][0] = (short)f2bf(u0[0]); fx[kk][1] = (short)f2bf(u0[1]);
      fx[kk][2] = (short)f2bf(u0[2]); fx[kk][3] = (short)f2bf(u0[3]);
      fx[kk][4] = (short)f2bf(u1[0]); fx[kk][5] = (short)f2bf(u1[1]);
      fx[kk][6] = (short)f2bf(u1[2]); fx[kk][7] = (short)f2bf(u1[3]);
    }
  }

  float sumG = 0.f, sqG = 0.f, sumX = 0.f, sqX = 0.f;

  // staging thread mapping (all global loads 128B-contiguous per instruction):
  // G: thread (gq=tid>>3 -> 4-ch group, gh=tid&7): float4 at s0+gh*4 (va)
  //    and s0+32+gh*4 (vb) for 4 channels -> rows gh*4+j and 32+gh*4+j.
  // X: thread (xq=tid>>4, xh=tid&15): float4 at s0+xh*4 for 4 channels.
  const int gq = tid >> 3;
  const int gh = tid & 7;
  const int xq = tid >> 4;
  const int xh = tid & 15;

  const float* gp0 = g + ((size_t)(batch * CG + gq * 4)) * NSP + gh * 4;
  const float* xp0 = x + ((size_t)(batch * CX + xq * 4)) * NSP + xh * 4;

  floatx4 va[4], vb[4], vx[4];

  auto loadTile = [&](int t) {
    const int s0 = t * TS;  // relative to sblk
#pragma unroll
    for (int dc = 0; dc < 4; ++dc) {
      va[dc] = *(const floatx4*)(gp0 + (size_t)dc * NSP + sblk + s0);
      vb[dc] = *(const floatx4*)(gp0 + (size_t)dc * NSP + sblk + s0 + 32);
      vx[dc] = *(const floatx4*)(xp0 + (size_t)dc * NSP + sblk + s0);
    }
  };

  loadTile(0);

  for (int t = 0; t < TPB; ++t) {
    __syncthreads();  // previous tile's LDS reads complete
    // stage regs -> LDS (fp32 -> bf16, transposed [s][c])
#pragma unroll
    for (int j = 0; j < 4; ++j) {
      ushort4 oa, ob, ox;
      oa.x = f2bf(va[0][j]); oa.y = f2bf(va[1][j]);
      oa.z = f2bf(va[2][j]); oa.w = f2bf(va[3][j]);
      ob.x = f2bf(vb[0][j]); ob.y = f2bf(vb[1][j]);
      ob.z = f2bf(vb[2][j]); ob.w = f2bf(vb[3][j]);
      ox.x = f2bf(vx[0][j]); ox.y = f2bf(vx[1][j]);
      ox.z = f2bf(vx[2][j]); ox.w = f2bf(vx[3][j]);
      *(ushort4*)&lG[(gh * 4 + j) * LGS + gq * 4]      = oa;
      *(ushort4*)&lG[(gh * 4 + 32 + j) * LGS + gq * 4] = ob;
      *(ushort4*)&lX[(xh * 4 + j) * LXS + xq * 4]      = ox;
    }
    __syncthreads();

    // issue next tile's global loads NOW -> in flight during MFMA+stores
    if (t + 1 < TPB) loadTile(t + 1);

    const int s0 = sblk + t * TS;
#pragma unroll
    for (int nt = 0; nt < 4; ++nt) {
      const int srow = nt * 16 + l16;
      floatx4 aG = {0.f, 0.f, 0.f, 0.f};
      floatx4 aX = {0.f, 0.f, 0.f, 0.f};
#pragma unroll
      for (int kk = 0; kk < 4; ++kk) {
        short8 bfr = *(const short8*)&lG[srow * LGS + kk * 32 + quad * 8];
        aG = __builtin_amdgcn_mfma_f32_16x16x32_bf16(fg[kk], bfr, aG, 0, 0, 0);
      }
#pragma unroll
      for (int kk = 0; kk < 2; ++kk) {
        short8 bfr = *(const short8*)&lX[srow * LXS + kk * 32 + quad * 8];
        aX = __builtin_amdgcn_mfma_f32_16x16x32_bf16(fx[kk], bfr, aX, 0, 0, 0);
      }
#pragma unroll
      for (int r = 0; r < 4; ++r) {
        sumG += aG[r]; sqG += aG[r] * aG[r];
        sumX += aX[r]; sqX += aX[r] * aX[r];
      }
      // D layout: row(oc) = quad*4+r, col(spatial) = lane&15.
      // Interleaved store: uint = (g1 bf16) | (x1 bf16 << 16); one 16B store
      // per lane -> wave writes 16 rows x 64B contiguous segments.
      const int s = s0 + nt * 16 + l16;
      uint4 ow;
      ow.x = (uint32_t)f2bf(aG[0]) | ((uint32_t)f2bf(aX[0]) << 16);
      ow.y = (uint32_t)f2bf(aG[1]) | ((uint32_t)f2bf(aX[1]) << 16);
      ow.z = (uint32_t)f2bf(aG[2]) | ((uint32_t)f2bf(aX[2]) << 16);
      ow.w = (uint32_t)f2bf(aG[3]) | ((uint32_t)f2bf(aX[3]) << 16);
      *(uint4*)(outp + ((size_t)batch * NSP + s) * CO + ocb + quad * 4) = ow;
    }
  }

  // all 4 values of a lane belong to group (4*wave + quad) >> 1;
  // lanes 0..31 -> group 2w, lanes 32..63 -> group 2w+1
#pragma unroll
  for (int m = 1; m <= 16; m <<= 1) {
    sumG += __shfl_xor(sumG, m); sqG += __shfl_xor(sqG, m);
    sumX += __shfl_xor(sumX, m); sqX += __shfl_xor(sqX, m);
  }
  if ((lane & 31) == 0) {
    const int grp = wave * 2 + (lane >> 5);
    float* sp = stats + ((size_t)batch * GROUPS + grp) * 4;
    atomicAdd(sp + 0, sumG); atomicAdd(sp + 1, sqG);
    atomicAdd(sp + 2, sumX); atomicAdd(sp + 3, sqX);
  }
}

// ---------------- K3: leaky(g1+x1) . psi_w  + psi stats ----------------
// Wave-cooperative: lane l reads one contiguous uint4 (4 oc-pairs of row
// idx>>4); wave load = 1KB contiguous. Partial psi-dot per lane, then
// shfl_xor(1,2,4,8) reduces the 16 lanes sharing a row.
// GN constants computed inline from stats (k2_const kernel eliminated).
__global__ __launch_bounds__(256, 4)
void k3_gate(const uint32_t* __restrict__ wsp, const float* __restrict__ stats,
             const float* __restrict__ wgw, const float* __restrict__ wgb,
             const float* __restrict__ wxw, const float* __restrict__ wxb,
             const float* __restrict__ psiw,
             float* __restrict__ ppre, float* __restrict__ psiSt)
{
  const int tid = threadIdx.x;
  const int batch = blockIdx.x >> 10;               // 1024 blocks per batch
  const int lane16 = tid & 15;

  // per-lane constants for ocs lane16*4 .. lane16*4+3
  float4 cst[4];
  {
    const float invn = 1.f / (float)(NSP * (CO / GROUPS));
#pragma unroll
    for (int j = 0; j < 4; ++j) {
      const int oc = lane16 * 4 + j;
      const float* sp = stats + ((size_t)batch * GROUPS + (oc >> 3)) * 4;
      float mG = sp[0] * invn, vG = sp[1] * invn - mG * mG;
      float mX = sp[2] * invn, vX = sp[3] * invn - mX * mX;
      float sG = wgw[oc] * rsqrtf(vG + EPS);
      float sX = wxw[oc] * rsqrtf(vX + EPS);
      cst[j] = make_float4(sG, sX, wgb[oc] - mG * sG + wxb[oc] - mX * sX, psiw[oc]);
    }
  }

  const uint4* basep = (const uint4*)(wsp + (size_t)batch * NSP * CO);
  const int blk = (blockIdx.x & 1023) * 4096;       // uint4 index within batch
  float* pout = ppre + (size_t)batch * NSP;

  uint4 v[16];
#pragma unroll
  for (int i = 0; i < 16; ++i) v[i] = basep[blk + i * 256 + tid];

  float ps = 0.f, pq = 0.f;
#pragma unroll
  for (int i = 0; i < 16; ++i) {
    const uint4 u = v[i];
    float p = 0.f;
    {
      float gg = bf2f(u.x & 0xffffu), xx = bf2f(u.x >> 16);
      float a = fmaf(gg, cst[0].x, fmaf(xx, cst[0].y, cst[0].z));
      a = (a >= 0.f) ? a : 0.01f * a; p = fmaf(cst[0].w, a, p);
    }
    {
      float gg = bf2f(u.y & 0xffffu), xx = bf2f(u.y >> 16);
      float a = fmaf(gg, cst[1].x, fmaf(xx, cst[1].y, cst[1].z));
      a = (a >= 0.f) ? a : 0.01f * a; p = fmaf(cst[1].w, a, p);
    }
    {
      float gg = bf2f(u.z & 0xffffu), xx = bf2f(u.z >> 16);
      float a = fmaf(gg, cst[2].x, fmaf(xx, cst[2].y, cst[2].z));
      a = (a >= 0.f) ? a : 0.01f * a; p = fmaf(cst[2].w, a, p);
    }
    {
      float gg = bf2f(u.w & 0xffffu), xx = bf2f(u.w >> 16);
      float a = fmaf(gg, cst[3].x, fmaf(xx, cst[3].y, cst[3].z));
      a = (a >= 0.f) ? a : 0.01f * a; p = fmaf(cst[3].w, a, p);
    }
    // reduce over the 16 lanes sharing this spatial row
    p += __shfl_xor(p, 1); p += __shfl_xor(p, 2);
    p += __shfl_xor(p, 4); p += __shfl_xor(p, 8);
    if (lane16 == 0) {
      const int idx = blk + i * 256 + tid;
      pout[idx >> 4] = p;
      ps += p; pq += p * p;
    }
  }

  // reduce ps,pq across the wave (nonzero only on lanes 0,16,32,48)
  ps += __shfl_xor(ps, 16); pq += __shfl_xor(pq, 16);
  ps += __shfl_xor(ps, 32); pq += __shfl_xor(pq, 32);
  __shared__ float red[8];
  const int wv = tid >> 6;
  if ((tid & 63) == 0) { red[wv * 2] = ps; red[wv * 2 + 1] = pq; }
  __syncthreads();
  if (tid == 0) {
    atomicAdd(&psiSt[batch * 2 + 0], red[0] + red[2] + red[4] + red[6]);
    atomicAdd(&psiSt[batch * 2 + 1], red[1] + red[3] + red[5] + red[7]);
  }
}

// ---------------- K4: psi = sigmoid(GN(p)), out = x * psi ----------------
__global__ __launch_bounds__(256, 4)
void k4_out(const float* __restrict__ x, const float* __restrict__ ppre,
            const float* __restrict__ psiSt, const float* __restrict__ pgw,
            const float* __restrict__ pgb, float* __restrict__ out)
{
  const size_t q = (size_t)blockIdx.x * 256 + threadIdx.x;  // 8,388,608 threads
  const int s4 = (int)(q & (NSP / 4 - 1)) * 4;
  const int cb = (int)(q >> 16);   // NSP/4 = 65536
  const int c  = cb & 63;
  const int b  = cb >> 6;
  const float inv = 1.f / (float)NSP;
  const float mean = psiSt[b * 2] * inv;
  const float var  = psiSt[b * 2 + 1] * inv - mean * mean;
  const float rstd = rsqrtf(var + EPS);
  const float w0 = pgw[0], b0 = pgb[0];
  float4 p  = *(const float4*)&ppre[(size_t)b * NSP + s4];
  float4 xv = *(const float4*)&x[((size_t)(b * CX + c)) * NSP + s4];
  float4 o;
  o.x = xv.x / (1.f + __expf(-(fmaf((p.x - mean) * rstd, w0, b0))));
  o.y = xv.y / (1.f + __expf(-(fmaf((p.y - mean) * rstd, w0, b0))));
  o.z = xv.z / (1.f + __expf(-(fmaf((p.z - mean) * rstd, w0, b0))));
  o.w = xv.w / (1.f + __expf(-(fmaf((p.w - mean) * rstd, w0, b0))));
  *(float4*)&out[((size_t)(b * CX + c)) * NSP + s4] = o;
}

extern "C" void kernel_launch(void* const* d_in, const int* in_sizes, int n_in,
                              void* d_out, int out_size, void* d_ws, size_t ws_size,
                              hipStream_t stream)
{
  const float* g     = (const float*)d_in[0];
  const float* x     = (const float*)d_in[1];
  const float* wgw   = (const float*)d_in[2];   // Wg_w [64][128]
  const float* wggnw = (const float*)d_in[3];
  const float* wggnb = (const float*)d_in[4];
  const float* wxw   = (const float*)d_in[5];   // Wx_w [64][64]
  const float* wxgnw = (const float*)d_in[6];
  const float* wxgnb = (const float*)d_in[7];
  const float* psiw  = (const float*)d_in[8];   // [1][64]
  const float* psgnw = (const float*)d_in[9];
  const float* psgnb = (const float*)d_in[10];

  char* ws = (char*)d_ws;
  uint32_t* wsp = (uint32_t*)ws;                             // 134,217,728 B
  float* ppre   = (float*)(ws + 134217728);                  // 2,097,152 B
  float* stats  = (float*)(ws + 136314880);                  // 256 B
  float* psiSt  = (float*)(ws + 136315136);                  // 16 B

  hipMemsetAsync(ws + 136314880, 0, 320, stream);  // stats + psiStats

  hipLaunchKernelGGL(k1_conv, dim3(1024), dim3(256), 0, stream,
                     g, x, wgw, wxw, wsp, stats);
  hipLaunchKernelGGL(k3_gate, dim3(2048), dim3(256), 0, stream,
                     wsp, stats, wggnw, wggnb, wxgnw, wxgnb, psiw, ppre, psiSt);
  hipLaunchKernelGGL(k4_out, dim3(32768), dim3(256), 0, stream,
                     x, ppre, psiSt, psgnw, psgnb, (float*)d_out);
}